// Round 13
// baseline (230.944 us; speedup 1.0000x reference)
//
#include <hip/hip_runtime.h>

#define RANK 128
#define LN_EPS 1e-5f

#define NCH 4
#define CHUNK 12800            // NCH*CHUNK = 51200 >= M ; LDS = 50 KB
#define BINS (NCH * CHUNK)
#define ECH 64
#define BT 1024
#define BMWMAX 1600            // bitmap words for M <= 51200
#define NSB 128

using short8 = __attribute__((ext_vector_type(8))) short;
using v4f    = __attribute__((ext_vector_type(4))) float;

__device__ inline unsigned short f2bf(float f) {
    unsigned u = __float_as_uint(f);
    unsigned r = (u + 0x7FFF + ((u >> 16) & 1)) >> 16;   // RNE
    return (unsigned short)r;
}

// ---- K1: full src histogram (u16 partials) + W repack + T3 mark ----
__global__ __launch_bounds__(BT) void hist_mark(const int* __restrict__ src,
                                                const float* __restrict__ Ws,
                                                short* __restrict__ Wt,
                                                const int* __restrict__ bnn, int nG,
                                                unsigned short* __restrict__ psrc,
                                                int* __restrict__ T3, int* __restrict__ map3,
                                                unsigned* __restrict__ bm3,
                                                int* __restrict__ mcnt3, int* __restrict__ cnt3,
                                                int nE, int M) {
    __shared__ int h[CHUNK];
    int c = blockIdx.x, n = blockIdx.y;
    int tid = threadIdx.x;
    if (c >= ECH) {
        int which = c - ECH;
        if (which == 1 && n == 3) {
            int bmw = (M + 31) / 32;
            for (int i = tid; i < bmw; i += BT) bm3[i] = 0;
            __syncthreads();
            if (tid < 64) {
                int lane = tid;
                if (nG <= 64) {
                    int v = (lane < nG) ? bnn[lane] : 0;
                    int orig = v;
#pragma unroll
                    for (int off = 1; off < 64; off <<= 1) {
                        int t = __shfl_up(v, off);
                        if (lane >= off) v += t;
                    }
                    int excl = v - orig;
                    if (lane < nG) {
                        T3[lane] = excl;
                        map3[excl] = lane;
                        atomicOr(&bm3[excl >> 5], 1u << (excl & 31));
                    }
                } else if (lane == 0) {
                    int idx = 0;
                    for (int g = 0; g < nG; g++) {
                        T3[g] = idx; map3[idx] = g;
                        atomicOr(&bm3[idx >> 5], 1u << (idx & 31));
                        idx += bnn[g];
                    }
                }
            }
            if (tid == 0) { *mcnt3 = 0; *cnt3 = nG; }
            return;
        }
        int sid;
        if (which == 0) sid = n * BT + tid;
        else { if (n >= 2) return; sid = 4096 + n * BT + tid; }
        if (sid < 3 * 2048) {
            int l = sid >> 11;
            int s = sid & 2047;
            int lane = s & 63, ct = (s >> 6) & 7, k0 = s >> 9;
            int m = lane & 15, quad = lane >> 4;
            const float* W = Ws + (size_t)l * RANK * RANK;
            short* o = Wt + (size_t)l * 16384 + (size_t)s * 8;
#pragma unroll
            for (int j = 0; j < 8; j++)
                o[j] = (short)f2bf(W[(k0 * 32 + quad * 8 + j) * RANK + ct * 16 + m]);
        }
        return;
    }
    int base = n * CHUNK;
    for (int i = tid; i < CHUNK; i += BT) h[i] = 0;
    __syncthreads();
    int epc = (nE + ECH - 1) / ECH;
    int e0 = c * epc, e1 = min(e0 + epc, nE);
    int a0 = min((e0 + 3) & ~3, e1);
    if (tid < a0 - e0) {
        int v = src[e0 + tid] - base;
        if ((unsigned)v < (unsigned)CHUNK) atomicAdd(&h[v], 1);
    }
    int rem = e1 - a0;
    int nv = (rem > 0) ? (rem & ~3) : 0;
    for (int e = a0 + tid * 4; e < a0 + nv; e += BT * 4) {
        int4 v4 = *(const int4*)(src + e);
        int v;
        v = v4.x - base; if ((unsigned)v < (unsigned)CHUNK) atomicAdd(&h[v], 1);
        v = v4.y - base; if ((unsigned)v < (unsigned)CHUNK) atomicAdd(&h[v], 1);
        v = v4.z - base; if ((unsigned)v < (unsigned)CHUNK) atomicAdd(&h[v], 1);
        v = v4.w - base; if ((unsigned)v < (unsigned)CHUNK) atomicAdd(&h[v], 1);
    }
    int t0 = a0 + nv;
    if (tid < e1 - t0) {
        int v = src[t0 + tid] - base;
        if ((unsigned)v < (unsigned)CHUNK) atomicAdd(&h[v], 1);
    }
    __syncthreads();
    unsigned short* o = psrc + (size_t)c * BINS + base;
    for (int i = tid; i < CHUNK; i += BT) o[i] = (unsigned short)h[i];
}

// ---- edge scan, two-phase compaction: ONE global atomic per block ----
template <int COUNT>
__device__ void scan_match_body(const int* __restrict__ src, const int* __restrict__ dst,
                                const unsigned* __restrict__ bm, int2* __restrict__ E,
                                int* __restrict__ mcnt, int* __restrict__ gcount,
                                const int* __restrict__ mapPrev,
                                int nE, int bid, int nblocks, int M) {
    __shared__ unsigned bmL[BMWMAX];
    __shared__ int wcnt[16];
    __shared__ int wbase[16];
    int tid = threadIdx.x;
    int w = tid >> 6, lane = tid & 63;
    int bmw = (M + 31) / 32;
    for (int i = tid; i < bmw; i += BT) bmL[i] = bm[i];
    __syncthreads();
    long long start = ((long long)bid * BT + tid) * 4;
    long long stride = (long long)nblocks * BT * 4;

    // phase 1: count matches per wave (+ per-slot counts if COUNT)
    int myc = 0;
    for (long long b0 = start; b0 < nE; b0 += stride) {
        int dv[4]; int c4;
        if (b0 + 4 <= nE) {
            int4 d4 = *(const int4*)(dst + b0);
            dv[0] = d4.x; dv[1] = d4.y; dv[2] = d4.z; dv[3] = d4.w;
            c4 = 4;
        } else {
            c4 = (int)(nE - b0);
            for (int j = 0; j < c4; j++) dv[j] = dst[b0 + j];
        }
#pragma unroll
        for (int j = 0; j < 4; j++) {
            bool flag = (j < c4) && ((bmL[dv[j] >> 5] >> (dv[j] & 31)) & 1);
            if (COUNT && flag) atomicAdd(&gcount[mapPrev[dv[j]]], 1);
            unsigned long long mask = __ballot(flag);
            if (lane == 0) myc += __popcll(mask);
        }
    }
    if (lane == 0) wcnt[w] = myc;
    __syncthreads();
    if (tid == 0) {
        int tot = 0;
#pragma unroll
        for (int k = 0; k < 16; k++) { wbase[k] = tot; tot += wcnt[k]; }
        int gb = atomicAdd(mcnt, tot);          // the ONLY global atomic
#pragma unroll
        for (int k = 0; k < 16; k++) wbase[k] += gb;
    }
    __syncthreads();

    // phase 2: re-scan (L2-hot), deterministic writes
    int woff = wbase[w];
    for (long long b0 = start; b0 < nE; b0 += stride) {
        int dv[4], sv[4]; int c4;
        if (b0 + 4 <= nE) {
            int4 d4 = *(const int4*)(dst + b0);
            int4 s4 = *(const int4*)(src + b0);
            dv[0] = d4.x; dv[1] = d4.y; dv[2] = d4.z; dv[3] = d4.w;
            sv[0] = s4.x; sv[1] = s4.y; sv[2] = s4.z; sv[3] = s4.w;
            c4 = 4;
        } else {
            c4 = (int)(nE - b0);
            for (int j = 0; j < c4; j++) { dv[j] = dst[b0 + j]; sv[j] = src[b0 + j]; }
        }
#pragma unroll
        for (int j = 0; j < 4; j++) {
            bool flag = (j < c4) && ((bmL[dv[j] >> 5] >> (dv[j] & 31)) & 1);
            unsigned long long mask = __ballot(flag);
            if (flag) E[woff + __popcll(mask & ((1ull << lane) - 1))] = make_int2(sv[j], dv[j]);
            woff += __popcll(mask);
        }
    }
}

// ---- K2: invout reduce (blocks < nbR) + T3 edge scan (rest) ----
__global__ __launch_bounds__(BT) void reduce_scan3(const unsigned short* __restrict__ psrc,
                                                   float* __restrict__ invout, int M, int nbR,
                                                   const int* __restrict__ src,
                                                   const int* __restrict__ dst,
                                                   const unsigned* __restrict__ bm3,
                                                   int2* __restrict__ E3, int* __restrict__ mcnt3,
                                                   int nE) {
    if ((int)blockIdx.x < nbR) {
        int gid = blockIdx.x * BT + threadIdx.x;
        if (gid < M) {
            int cs = 0;
#pragma unroll 8
            for (int c = 0; c < ECH; c++) cs += psrc[(size_t)c * BINS + gid];
            invout[gid] = rsqrtf(fmaxf((float)cs, 1.0f));
        }
        return;
    }
    scan_match_body<0>(src, dst, bm3, E3, mcnt3, nullptr, nullptr, nE,
                       blockIdx.x - nbR, gridDim.x - nbR, M);
}

template <int COUNT>
__global__ __launch_bounds__(BT) void scan_match(const int* __restrict__ src,
                                                 const int* __restrict__ dst,
                                                 const unsigned* __restrict__ bm,
                                                 int2* __restrict__ E, int* __restrict__ mcnt,
                                                 int* __restrict__ gcount,
                                                 const int* __restrict__ mapPrev, int nE, int M) {
    scan_match_body<COUNT>(src, dst, bm, E, mcnt, gcount, mapPrev, nE,
                           blockIdx.x, gridDim.x, M);
}

// ---- single-block level builder (ballot-aggregated slot allocation) ----
__global__ __launch_bounds__(BT) void build_level(const int2* __restrict__ E,
                                                  const int* __restrict__ mcnt,
                                                  const int* __restrict__ mapPrev,
                                                  const int* __restrict__ cntPrev,
                                                  const float* __restrict__ invout,
                                                  int* __restrict__ Tnew, int* __restrict__ mapNew,
                                                  int* __restrict__ cntNew, float* __restrict__ soNew,
                                                  int* __restrict__ csrPrev, int* __restrict__ endsPrev,
                                                  float* __restrict__ invinPrev,
                                                  unsigned* __restrict__ bmNew,
                                                  int* __restrict__ mcntNext,
                                                  int* __restrict__ gzero, int M) {
    __shared__ unsigned bmL[BMWMAX];
    __shared__ int cntL[CHUNK];
    __shared__ int tmp[BT];
    __shared__ int lcnt;
    int tid = threadIdx.x;
    int lane = tid & 63;
    int bmw = (M + 31) / 32;
    int m = *mcnt;
    int nPrev = *cntPrev;
    for (int i = tid; i < bmw; i += BT) bmL[i] = 0;
    for (int i = tid; i < nPrev; i += BT) cntL[i] = 0;
    if (tid == 0) lcnt = 0;
    __syncthreads();
    // phase 1: frontier discovery (wave-aggregated slot alloc) + per-slot counts
    for (int i0 = 0; i0 < m; i0 += BT) {
        int i = i0 + tid;
        int u = 0;
        bool flag = false;
        if (i < m) {
            int2 e = E[i];
            u = e.x;
            unsigned old = atomicOr(&bmL[u >> 5], 1u << (u & 31));
            flag = !((old >> (u & 31)) & 1);
            atomicAdd(&cntL[mapPrev[e.y]], 1);
        }
        unsigned long long mask = __ballot(flag);
        if (mask) {
            int leader = __ffsll((long long)mask) - 1;
            int sl0 = 0;
            if (lane == leader) sl0 = atomicAdd(&lcnt, __popcll(mask));
            sl0 = __shfl(sl0, leader);
            if (flag) {
                int sl = sl0 + __popcll(mask & ((1ull << lane) - 1));
                Tnew[sl] = u;
                mapNew[u] = sl;
                soNew[sl] = invout[u];
            }
        }
    }
    __syncthreads();
    int carry = 0;
    for (int c0 = 0; c0 < nPrev; c0 += BT) {
        int v = (c0 + tid < nPrev) ? cntL[c0 + tid] : 0;
        __syncthreads();
        tmp[tid] = v;
        __syncthreads();
        for (int off = 1; off < BT; off <<= 1) {
            int t = (tid >= off) ? tmp[tid - off] : 0;
            __syncthreads();
            tmp[tid] += t;
            __syncthreads();
        }
        int incl = tmp[tid] + carry;
        int tot = tmp[BT - 1];
        if (c0 + tid < nPrev) {
            endsPrev[c0 + tid] = incl;
            invinPrev[c0 + tid] = rsqrtf(fmaxf((float)v, 1.0f));
            cntL[c0 + tid] = incl - v;
        }
        carry += tot;
    }
    __syncthreads();
    for (int i = tid; i < m; i += BT) {
        int2 e = E[i];
        int pos = atomicAdd(&cntL[mapPrev[e.y]], 1);
        csrPrev[pos] = mapNew[e.x];
    }
    __syncthreads();
    for (int i = tid; i < bmw; i += BT) bmNew[i] = bmL[i];
    int L = lcnt;
    if (gzero) for (int i = tid; i < L; i += BT) gzero[i] = 0;
    if (tid == 0) { *cntNew = L; *mcntNext = 0; }
}

// ---- T1 cursor scan (single block) ----
__global__ __launch_bounds__(BT) void cursors_kernel(const int* __restrict__ gcount,
                                                     const int* __restrict__ cnt1,
                                                     int* __restrict__ ends1,
                                                     float* __restrict__ invin1,
                                                     int* __restrict__ gcursor) {
    __shared__ int tmp[BT];
    int tid = threadIdx.x;
    int n1 = *cnt1;
    int carry = 0;
    for (int c0 = 0; c0 < n1; c0 += BT) {
        int v = (c0 + tid < n1) ? gcount[c0 + tid] : 0;
        __syncthreads();
        tmp[tid] = v;
        __syncthreads();
        for (int off = 1; off < BT; off <<= 1) {
            int t = (tid >= off) ? tmp[tid - off] : 0;
            __syncthreads();
            tmp[tid] += t;
            __syncthreads();
        }
        int incl = tmp[tid] + carry;
        int tot = tmp[BT - 1];
        if (c0 + tid < n1) {
            ends1[c0 + tid] = incl;
            invin1[c0 + tid] = rsqrtf(fmaxf((float)v, 1.0f));
            gcursor[c0 + tid] = incl - v;
        }
        carry += tot;
    }
}

// ---- T1 CSR fill ----
__global__ __launch_bounds__(BT) void fill1_kernel(const int2* __restrict__ E1,
                                                   const int* __restrict__ mcnt1,
                                                   const int* __restrict__ map1,
                                                   int* __restrict__ gcursor,
                                                   int* __restrict__ csr1) {
    int m = *mcnt1;
    for (int i = blockIdx.x * BT + threadIdx.x; i < m; i += gridDim.x * BT) {
        int2 e = E1[i];
        int pos = atomicAdd(&gcursor[map1[e.y]], 1);
        csr1[pos] = e.x;
    }
}

// ---- fused layer: slot-dense CSR gather (LDS) + bf16 MFMA + invin/bias/LN/ReLU ----
template <int LAST, int FP32IN>
__global__ __launch_bounds__(256) void layer_fused(const void* __restrict__ FinV,
                                                   const float* __restrict__ edge_scale,
                                                   const int* __restrict__ ends,
                                                   const int* __restrict__ csr,
                                                   const short* __restrict__ Wt,
                                                   const float* __restrict__ invin_slot,
                                                   const float* __restrict__ so_slot,
                                                   const float* __restrict__ bias,
                                                   const float* __restrict__ gamma,
                                                   const float* __restrict__ beta,
                                                   const int* __restrict__ cnt,
                                                   unsigned short* __restrict__ Fout,
                                                   float* __restrict__ out) {
    const unsigned* Fb = (const unsigned*)FinV;
    const float4*  Ff = (const float4*)FinV;
    __shared__ short As[16][136];
    __shared__ float sstat[2][4][16];
    __shared__ float sinv[2][16];
    int tid = threadIdx.x;
    int w = tid >> 6, lane = tid & 63;
    int seg = lane >> 4, m = lane & 15;
    int n = *cnt;
    int tiles = (n + 15) >> 4;

    float bb[2], gg[2], pp[2];
#pragma unroll
    for (int j = 0; j < 2; j++) {
        int col = (w * 2 + j) * 16 + m;
        bb[j] = bias[col]; gg[j] = gamma[col]; pp[j] = beta[col];
    }

    for (int t = blockIdx.x; t < tiles; t += gridDim.x) {
        int base = t * 16;

        for (int q = 0; q < 4; q++) {
            int rr = w * 4 + q;
            int gr = base + rr;
            float ax[8];
#pragma unroll
            for (int k = 0; k < 8; k++) ax[k] = 0.f;
            if (gr < n) {
                int end = ends[gr];
                int e = (gr == 0) ? 0 : ends[gr - 1];
                while (e < end) {
                    int rem = end - e;
                    int myi = 0;
                    if (lane < rem) myi = csr[e + lane];
                    int nn = min(rem, 64);
                    int p = 0;
                    for (; p + 16 <= nn; p += 16) {
                        if (FP32IN) {
                            float4 fa[4], fb4[4]; float so[4];
#pragma unroll
                            for (int gi = 0; gi < 4; gi++) {
                                int idx = __shfl(myi, p + gi * 4 + seg);
                                so[gi] = edge_scale[idx];
                                const float4* qq = Ff + (size_t)idx * 32 + m * 2;
                                fa[gi] = qq[0]; fb4[gi] = qq[1];
                            }
#pragma unroll
                            for (int gi = 0; gi < 4; gi++) {
                                ax[0] += fa[gi].x * so[gi]; ax[1] += fa[gi].y * so[gi];
                                ax[2] += fa[gi].z * so[gi]; ax[3] += fa[gi].w * so[gi];
                                ax[4] += fb4[gi].x * so[gi]; ax[5] += fb4[gi].y * so[gi];
                                ax[6] += fb4[gi].z * so[gi]; ax[7] += fb4[gi].w * so[gi];
                            }
                        } else {
                            uint4 u[4];
#pragma unroll
                            for (int gi = 0; gi < 4; gi++) {
                                int idx = __shfl(myi, p + gi * 4 + seg);
                                u[gi] = *(const uint4*)(Fb + (size_t)idx * 64 + m * 4);
                            }
#pragma unroll
                            for (int gi = 0; gi < 4; gi++) {
                                ax[0] += __uint_as_float(u[gi].x << 16);
                                ax[1] += __uint_as_float(u[gi].x & 0xFFFF0000u);
                                ax[2] += __uint_as_float(u[gi].y << 16);
                                ax[3] += __uint_as_float(u[gi].y & 0xFFFF0000u);
                                ax[4] += __uint_as_float(u[gi].z << 16);
                                ax[5] += __uint_as_float(u[gi].z & 0xFFFF0000u);
                                ax[6] += __uint_as_float(u[gi].w << 16);
                                ax[7] += __uint_as_float(u[gi].w & 0xFFFF0000u);
                            }
                        }
                    }
                    for (; p < nn; p += 4) {
                        bool act = (p + seg) < nn;
                        int idx = __shfl(myi, (p + seg) & 63);
                        if (act) {
                            if (FP32IN) {
                                float so = edge_scale[idx];
                                const float4* qq = Ff + (size_t)idx * 32 + m * 2;
                                float4 fa = qq[0], fb4 = qq[1];
                                ax[0] += fa.x * so; ax[1] += fa.y * so;
                                ax[2] += fa.z * so; ax[3] += fa.w * so;
                                ax[4] += fb4.x * so; ax[5] += fb4.y * so;
                                ax[6] += fb4.z * so; ax[7] += fb4.w * so;
                            } else {
                                uint4 u = *(const uint4*)(Fb + (size_t)idx * 64 + m * 4);
                                ax[0] += __uint_as_float(u.x << 16);
                                ax[1] += __uint_as_float(u.x & 0xFFFF0000u);
                                ax[2] += __uint_as_float(u.y << 16);
                                ax[3] += __uint_as_float(u.y & 0xFFFF0000u);
                                ax[4] += __uint_as_float(u.z << 16);
                                ax[5] += __uint_as_float(u.z & 0xFFFF0000u);
                                ax[6] += __uint_as_float(u.w << 16);
                                ax[7] += __uint_as_float(u.w & 0xFFFF0000u);
                            }
                        }
                    }
                    e += nn;
                }
#pragma unroll
                for (int k = 0; k < 8; k++) {
                    ax[k] += __shfl_xor(ax[k], 16);
                    ax[k] += __shfl_xor(ax[k], 32);
                }
            }
            if (seg == 0) {
                uint4 o;
                o.x = (unsigned)f2bf(ax[0]) | ((unsigned)f2bf(ax[1]) << 16);
                o.y = (unsigned)f2bf(ax[2]) | ((unsigned)f2bf(ax[3]) << 16);
                o.z = (unsigned)f2bf(ax[4]) | ((unsigned)f2bf(ax[5]) << 16);
                o.w = (unsigned)f2bf(ax[6]) | ((unsigned)f2bf(ax[7]) << 16);
                *(uint4*)&As[rr][8 * m] = o;
            }
            if (lane == 0) {
                sinv[0][rr] = (gr < n) ? invin_slot[gr] : 1.f;
                sinv[1][rr] = (LAST || gr >= n) ? 1.f : so_slot[gr];
            }
        }
        __syncthreads();

        short8 a[4];
#pragma unroll
        for (int k0 = 0; k0 < 4; k0++)
            a[k0] = *(const short8*)&As[m][k0 * 32 + seg * 8];
        v4f acc[2];
        acc[0] = (v4f){0.f, 0.f, 0.f, 0.f};
        acc[1] = (v4f){0.f, 0.f, 0.f, 0.f};
#pragma unroll
        for (int k0 = 0; k0 < 4; k0++) {
#pragma unroll
            for (int j = 0; j < 2; j++) {
                int ct = w * 2 + j;
                short8 b = *(const short8*)(Wt + (size_t)((k0 * 8 + ct) * 64 + lane) * 8);
                acc[j] = __builtin_amdgcn_mfma_f32_16x16x32_bf16(a[k0], b, acc[j], 0, 0, 0);
            }
        }

        float x[4][2];
#pragma unroll
        for (int r = 0; r < 4; r++) {
            int row = seg * 4 + r;
            float iv = sinv[0][row];
            float s = 0.f, sq = 0.f;
#pragma unroll
            for (int j = 0; j < 2; j++) {
                float c = acc[j][r] * iv + bb[j];
                x[r][j] = c;
                s += c; sq += c * c;
            }
#pragma unroll
            for (int off = 1; off < 16; off <<= 1) {
                s  += __shfl_xor(s, off);
                sq += __shfl_xor(sq, off);
            }
            if (m == 0) { sstat[0][w][row] = s; sstat[1][w][row] = sq; }
        }
        __syncthreads();

#pragma unroll
        for (int r = 0; r < 4; r++) {
            int row = seg * 4 + r;
            int gr = base + row;
            if (gr >= n) continue;
            float s  = sstat[0][0][row] + sstat[0][1][row] + sstat[0][2][row] + sstat[0][3][row];
            float sq = sstat[1][0][row] + sstat[1][1][row] + sstat[1][2][row] + sstat[1][3][row];
            float mu = s * (1.0f / RANK);
            float var = sq * (1.0f / RANK) - mu * mu;
            float rs = rsqrtf(var + LN_EPS);
#pragma unroll
            for (int j = 0; j < 2; j++) {
                int col = (w * 2 + j) * 16 + m;
                float y = fmaxf((x[r][j] - mu) * rs * gg[j] + pp[j], 0.f);
                if (LAST) out[(size_t)gr * RANK + col] = y;
                else Fout[(size_t)gr * RANK + col] = f2bf(y * sinv[1][row]);
            }
        }
        __syncthreads();
    }
}

extern "C" void kernel_launch(void* const* d_in, const int* in_sizes, int n_in,
                              void* d_out, int out_size, void* d_ws, size_t ws_size,
                              hipStream_t stream) {
    const float* features = (const float*)d_in[0];
    const int* src = (const int*)d_in[1];
    const int* dst = (const int*)d_in[2];
    const int* bnn = (const int*)d_in[3];
    const float* Ws = (const float*)d_in[4];
    const float* bs = (const float*)d_in[5];
    const float* gammas = (const float*)d_in[6];
    const float* betas = (const float*)d_in[7];
    float* out = (float*)d_out;

    int M  = in_sizes[0] / RANK;   // 50000
    int nE = in_sizes[1];          // 640000
    int nG = in_sizes[3];          // 50

    char* ws = (char*)d_ws;
    size_t off = 0;
    auto alloc = [&](size_t bytes) {
        void* p = ws + off;
        off += (bytes + 255) & ~(size_t)255;
        return p;
    };
    unsigned short* psrc = (unsigned short*)alloc((size_t)ECH * BINS * 2);
    short* Wt      = (short*)alloc((size_t)3 * 16384 * 2);
    float* invout  = (float*)alloc((size_t)M * 4);
    int*   map3    = (int*)alloc((size_t)M * 4);
    int*   map2    = (int*)alloc((size_t)M * 4);
    int*   map1    = (int*)alloc((size_t)M * 4);
    int*   T3      = (int*)alloc((size_t)((nG + 63) & ~63) * 4);
    int*   T2      = (int*)alloc((size_t)M * 4);
    int*   T1      = (int*)alloc((size_t)M * 4);
    float* so2     = (float*)alloc((size_t)M * 4);
    float* so1     = (float*)alloc((size_t)M * 4);
    float* invin3  = (float*)alloc((size_t)((nG + 63) & ~63) * 4);
    float* invin2  = (float*)alloc((size_t)M * 4);
    float* invin1  = (float*)alloc((size_t)M * 4);
    int*   ends3   = (int*)alloc((size_t)((nG + 63) & ~63) * 4);
    int*   ends2   = (int*)alloc((size_t)M * 4);
    int*   ends1   = (int*)alloc((size_t)M * 4);
    int*   csr3    = (int*)alloc((size_t)nE * 4);
    int*   csr2    = (int*)alloc((size_t)nE * 4);
    int*   csr1    = (int*)alloc((size_t)nE * 4);
    int2*  E3      = (int2*)alloc((size_t)nE * 8);
    int2*  E2      = (int2*)alloc((size_t)nE * 8);
    int2*  E1      = (int2*)alloc((size_t)nE * 8);
    unsigned* bm3  = (unsigned*)alloc(BMWMAX * 4);
    unsigned* bm2  = (unsigned*)alloc(BMWMAX * 4);
    unsigned* bm1  = (unsigned*)alloc(BMWMAX * 4);
    int*   mcnt3   = (int*)alloc(256);
    int*   mcnt2   = (int*)alloc(256);
    int*   mcnt1   = (int*)alloc(256);
    int*   cnt3    = (int*)alloc(256);
    int*   cnt2    = (int*)alloc(256);
    int*   cnt1    = (int*)alloc(256);
    int*   gcount  = (int*)alloc((size_t)M * 4);
    int*   gcursor = (int*)alloc((size_t)M * 4);
    short* F1      = (short*)alloc((size_t)M * RANK * 2);
    short* F2      = (short*)alloc((size_t)M * RANK * 2);

    int nbR = (M + BT - 1) / BT;

    hist_mark<<<dim3(ECH + 2, NCH), BT, 0, stream>>>(src, Ws, Wt, bnn, nG, psrc,
                                                     T3, map3, bm3, mcnt3, cnt3, nE, M);
    reduce_scan3<<<nbR + NSB, BT, 0, stream>>>(psrc, invout, M, nbR, src, dst, bm3, E3, mcnt3, nE);
    build_level<<<1, BT, 0, stream>>>(E3, mcnt3, map3, cnt3, invout, T2, map2, cnt2, so2,
                                      csr3, ends3, invin3, bm2, mcnt2, nullptr, M);
    scan_match<0><<<NSB, BT, 0, stream>>>(src, dst, bm2, E2, mcnt2, nullptr, nullptr, nE, M);
    build_level<<<1, BT, 0, stream>>>(E2, mcnt2, map2, cnt2, invout, T1, map1, cnt1, so1,
                                      csr2, ends2, invin2, bm1, mcnt1, gcount, M);
    scan_match<1><<<NSB, BT, 0, stream>>>(src, dst, bm1, E1, mcnt1, gcount, map1, nE, M);
    cursors_kernel<<<1, BT, 0, stream>>>(gcount, cnt1, ends1, invin1, gcursor);
    fill1_kernel<<<32, BT, 0, stream>>>(E1, mcnt1, map1, gcursor, csr1);

    layer_fused<0, 1><<<512, 256, 0, stream>>>(features, invout, ends1, csr1, Wt,
                                               invin1, so1, bs, gammas, betas, cnt1,
                                               (unsigned short*)F1, nullptr);
    layer_fused<0, 0><<<64, 256, 0, stream>>>(F1, nullptr, ends2, csr2, Wt + 16384,
                                              invin2, so2, bs + RANK, gammas + RANK, betas + RANK,
                                              cnt2, (unsigned short*)F2, nullptr);
    layer_fused<1, 0><<<(nG + 15) / 16, 256, 0, stream>>>(F2, nullptr, ends3, csr3, Wt + 32768,
                                                          invin3, nullptr, bs + 2 * RANK,
                                                          gammas + 2 * RANK, betas + 2 * RANK,
                                                          cnt3, nullptr, out);
}

// Round 14
// 199.339 us; speedup vs baseline: 1.1585x; 1.1585x over previous
//
#include <hip/hip_runtime.h>

#define RANK 128
#define LN_EPS 1e-5f

#define NCH 4
#define CHUNK 12800            // NCH*CHUNK = 51200 >= M ; LDS = 50 KB
#define BINS (NCH * CHUNK)
#define ECH 64
#define BT 1024
#define BMWMAX 1600            // bitmap words for M <= 51200
#define NSB 128

using short8 = __attribute__((ext_vector_type(8))) short;
using v4f    = __attribute__((ext_vector_type(4))) float;

__device__ inline unsigned short f2bf(float f) {
    unsigned u = __float_as_uint(f);
    unsigned r = (u + 0x7FFF + ((u >> 16) & 1)) >> 16;   // RNE
    return (unsigned short)r;
}

// ---- K1: full src histogram (u16 partials) + W repack + T3 mark ----
__global__ __launch_bounds__(BT) void hist_mark(const int* __restrict__ src,
                                                const float* __restrict__ Ws,
                                                short* __restrict__ Wt,
                                                const int* __restrict__ bnn, int nG,
                                                unsigned short* __restrict__ psrc,
                                                int* __restrict__ T3, int* __restrict__ map3,
                                                unsigned* __restrict__ bm3,
                                                int* __restrict__ mcnt3, int* __restrict__ cnt3,
                                                int nE, int M) {
    __shared__ int h[CHUNK];
    int c = blockIdx.x, n = blockIdx.y;
    int tid = threadIdx.x;
    if (c >= ECH) {
        int which = c - ECH;
        if (which == 1 && n == 3) {
            int bmw = (M + 31) / 32;
            for (int i = tid; i < bmw; i += BT) bm3[i] = 0;
            __syncthreads();
            if (tid < 64) {
                int lane = tid;
                if (nG <= 64) {
                    int v = (lane < nG) ? bnn[lane] : 0;
                    int orig = v;
#pragma unroll
                    for (int off = 1; off < 64; off <<= 1) {
                        int t = __shfl_up(v, off);
                        if (lane >= off) v += t;
                    }
                    int excl = v - orig;
                    if (lane < nG) {
                        T3[lane] = excl;
                        map3[excl] = lane;
                        atomicOr(&bm3[excl >> 5], 1u << (excl & 31));
                    }
                } else if (lane == 0) {
                    int idx = 0;
                    for (int g = 0; g < nG; g++) {
                        T3[g] = idx; map3[idx] = g;
                        atomicOr(&bm3[idx >> 5], 1u << (idx & 31));
                        idx += bnn[g];
                    }
                }
            }
            if (tid == 0) { *mcnt3 = 0; *cnt3 = nG; }
            return;
        }
        int sid;
        if (which == 0) sid = n * BT + tid;
        else { if (n >= 2) return; sid = 4096 + n * BT + tid; }
        if (sid < 3 * 2048) {
            int l = sid >> 11;
            int s = sid & 2047;
            int lane = s & 63, ct = (s >> 6) & 7, k0 = s >> 9;
            int m = lane & 15, quad = lane >> 4;
            const float* W = Ws + (size_t)l * RANK * RANK;
            short* o = Wt + (size_t)l * 16384 + (size_t)s * 8;
#pragma unroll
            for (int j = 0; j < 8; j++)
                o[j] = (short)f2bf(W[(k0 * 32 + quad * 8 + j) * RANK + ct * 16 + m]);
        }
        return;
    }
    int base = n * CHUNK;
    for (int i = tid; i < CHUNK; i += BT) h[i] = 0;
    __syncthreads();
    int epc = (nE + ECH - 1) / ECH;
    int e0 = c * epc, e1 = min(e0 + epc, nE);
    int a0 = min((e0 + 3) & ~3, e1);
    if (tid < a0 - e0) {
        int v = src[e0 + tid] - base;
        if ((unsigned)v < (unsigned)CHUNK) atomicAdd(&h[v], 1);
    }
    int rem = e1 - a0;
    int nv = (rem > 0) ? (rem & ~3) : 0;
    for (int e = a0 + tid * 4; e < a0 + nv; e += BT * 4) {
        int4 v4 = *(const int4*)(src + e);
        int v;
        v = v4.x - base; if ((unsigned)v < (unsigned)CHUNK) atomicAdd(&h[v], 1);
        v = v4.y - base; if ((unsigned)v < (unsigned)CHUNK) atomicAdd(&h[v], 1);
        v = v4.z - base; if ((unsigned)v < (unsigned)CHUNK) atomicAdd(&h[v], 1);
        v = v4.w - base; if ((unsigned)v < (unsigned)CHUNK) atomicAdd(&h[v], 1);
    }
    int t0 = a0 + nv;
    if (tid < e1 - t0) {
        int v = src[t0 + tid] - base;
        if ((unsigned)v < (unsigned)CHUNK) atomicAdd(&h[v], 1);
    }
    __syncthreads();
    unsigned short* o = psrc + (size_t)c * BINS + base;
    for (int i = tid; i < CHUNK; i += BT) o[i] = (unsigned short)h[i];
}

// ---- edge scan, two-phase compaction: ONE global atomic per block ----
template <int COUNT>
__device__ void scan_match_body(const int* __restrict__ src, const int* __restrict__ dst,
                                const unsigned* __restrict__ bm, int2* __restrict__ E,
                                int* __restrict__ mcnt, int* __restrict__ gcount,
                                const int* __restrict__ mapPrev,
                                int nE, int bid, int nblocks, int M) {
    __shared__ unsigned bmL[BMWMAX];
    __shared__ int wcnt[16];
    __shared__ int wbase[16];
    int tid = threadIdx.x;
    int w = tid >> 6, lane = tid & 63;
    int bmw = (M + 31) / 32;
    for (int i = tid; i < bmw; i += BT) bmL[i] = bm[i];
    __syncthreads();
    long long start = ((long long)bid * BT + tid) * 4;
    long long stride = (long long)nblocks * BT * 4;

    int myc = 0;
    for (long long b0 = start; b0 < nE; b0 += stride) {
        int dv[4]; int c4;
        if (b0 + 4 <= nE) {
            int4 d4 = *(const int4*)(dst + b0);
            dv[0] = d4.x; dv[1] = d4.y; dv[2] = d4.z; dv[3] = d4.w;
            c4 = 4;
        } else {
            c4 = (int)(nE - b0);
            for (int j = 0; j < c4; j++) dv[j] = dst[b0 + j];
        }
#pragma unroll
        for (int j = 0; j < 4; j++) {
            bool flag = (j < c4) && ((bmL[dv[j] >> 5] >> (dv[j] & 31)) & 1);
            if (COUNT && flag) atomicAdd(&gcount[mapPrev[dv[j]]], 1);
            unsigned long long mask = __ballot(flag);
            if (lane == 0) myc += __popcll(mask);
        }
    }
    if (lane == 0) wcnt[w] = myc;
    __syncthreads();
    if (tid == 0) {
        int tot = 0;
#pragma unroll
        for (int k = 0; k < 16; k++) { wbase[k] = tot; tot += wcnt[k]; }
        int gb = atomicAdd(mcnt, tot);          // the ONLY same-address global atomic
#pragma unroll
        for (int k = 0; k < 16; k++) wbase[k] += gb;
    }
    __syncthreads();

    int woff = wbase[w];
    for (long long b0 = start; b0 < nE; b0 += stride) {
        int dv[4], sv[4]; int c4;
        if (b0 + 4 <= nE) {
            int4 d4 = *(const int4*)(dst + b0);
            int4 s4 = *(const int4*)(src + b0);
            dv[0] = d4.x; dv[1] = d4.y; dv[2] = d4.z; dv[3] = d4.w;
            sv[0] = s4.x; sv[1] = s4.y; sv[2] = s4.z; sv[3] = s4.w;
            c4 = 4;
        } else {
            c4 = (int)(nE - b0);
            for (int j = 0; j < c4; j++) { dv[j] = dst[b0 + j]; sv[j] = src[b0 + j]; }
        }
#pragma unroll
        for (int j = 0; j < 4; j++) {
            bool flag = (j < c4) && ((bmL[dv[j] >> 5] >> (dv[j] & 31)) & 1);
            unsigned long long mask = __ballot(flag);
            if (flag) E[woff + __popcll(mask & ((1ull << lane) - 1))] = make_int2(sv[j], dv[j]);
            woff += __popcll(mask);
        }
    }
}

// ---- K2: invout reduce (blocks < nbR) + T3 edge scan (rest) ----
__global__ __launch_bounds__(BT) void reduce_scan3(const unsigned short* __restrict__ psrc,
                                                   float* __restrict__ invout, int M, int nbR,
                                                   const int* __restrict__ src,
                                                   const int* __restrict__ dst,
                                                   const unsigned* __restrict__ bm3,
                                                   int2* __restrict__ E3, int* __restrict__ mcnt3,
                                                   int nE) {
    if ((int)blockIdx.x < nbR) {
        int gid = blockIdx.x * BT + threadIdx.x;
        if (gid < M) {
            int cs = 0;
#pragma unroll 8
            for (int c = 0; c < ECH; c++) cs += psrc[(size_t)c * BINS + gid];
            invout[gid] = rsqrtf(fmaxf((float)cs, 1.0f));
        }
        return;
    }
    scan_match_body<0>(src, dst, bm3, E3, mcnt3, nullptr, nullptr, nE,
                       blockIdx.x - nbR, gridDim.x - nbR, M);
}

template <int COUNT>
__global__ __launch_bounds__(BT) void scan_match(const int* __restrict__ src,
                                                 const int* __restrict__ dst,
                                                 const unsigned* __restrict__ bm,
                                                 int2* __restrict__ E, int* __restrict__ mcnt,
                                                 int* __restrict__ gcount,
                                                 const int* __restrict__ mapPrev, int nE, int M) {
    scan_match_body<COUNT>(src, dst, bm, E, mcnt, gcount, mapPrev, nE,
                           blockIdx.x, gridDim.x, M);
}

// ---- single-block level-3 builder (small: ~640 edges, 50 prev slots) ----
// also zeroes bm1 global + cnt1 for the downstream multi-block discover
__global__ __launch_bounds__(BT) void build_level(const int2* __restrict__ E,
                                                  const int* __restrict__ mcnt,
                                                  const int* __restrict__ mapPrev,
                                                  const int* __restrict__ cntPrev,
                                                  const float* __restrict__ invout,
                                                  int* __restrict__ Tnew, int* __restrict__ mapNew,
                                                  int* __restrict__ cntNew, float* __restrict__ soNew,
                                                  int* __restrict__ csrPrev, int* __restrict__ endsPrev,
                                                  float* __restrict__ invinPrev,
                                                  unsigned* __restrict__ bmNew,
                                                  int* __restrict__ mcntNext,
                                                  int* __restrict__ gzero,
                                                  unsigned* __restrict__ bmZeroG,
                                                  int* __restrict__ cntZeroG, int M) {
    __shared__ unsigned bmL[BMWMAX];
    __shared__ int cntL[CHUNK];
    __shared__ int tmp[BT];
    __shared__ int lcnt;
    int tid = threadIdx.x;
    int lane = tid & 63;
    int bmw = (M + 31) / 32;
    int m = *mcnt;
    int nPrev = *cntPrev;
    for (int i = tid; i < bmw; i += BT) { bmL[i] = 0; bmZeroG[i] = 0; }
    for (int i = tid; i < nPrev; i += BT) cntL[i] = 0;
    if (tid == 0) { lcnt = 0; *cntZeroG = 0; }
    __syncthreads();
    for (int i0 = 0; i0 < m; i0 += BT) {
        int i = i0 + tid;
        int u = 0;
        bool flag = false;
        if (i < m) {
            int2 e = E[i];
            u = e.x;
            unsigned old = atomicOr(&bmL[u >> 5], 1u << (u & 31));
            flag = !((old >> (u & 31)) & 1);
            atomicAdd(&cntL[mapPrev[e.y]], 1);
        }
        unsigned long long mask = __ballot(flag);
        if (mask) {
            int leader = __ffsll((long long)mask) - 1;
            int sl0 = 0;
            if (lane == leader) sl0 = atomicAdd(&lcnt, __popcll(mask));
            sl0 = __shfl(sl0, leader);
            if (flag) {
                int sl = sl0 + __popcll(mask & ((1ull << lane) - 1));
                Tnew[sl] = u;
                mapNew[u] = sl;
                soNew[sl] = invout[u];
            }
        }
    }
    __syncthreads();
    int carry = 0;
    for (int c0 = 0; c0 < nPrev; c0 += BT) {
        int v = (c0 + tid < nPrev) ? cntL[c0 + tid] : 0;
        __syncthreads();
        tmp[tid] = v;
        __syncthreads();
        for (int off = 1; off < BT; off <<= 1) {
            int t = (tid >= off) ? tmp[tid - off] : 0;
            __syncthreads();
            tmp[tid] += t;
            __syncthreads();
        }
        int incl = tmp[tid] + carry;
        int tot = tmp[BT - 1];
        if (c0 + tid < nPrev) {
            endsPrev[c0 + tid] = incl;
            invinPrev[c0 + tid] = rsqrtf(fmaxf((float)v, 1.0f));
            cntL[c0 + tid] = incl - v;
        }
        carry += tot;
    }
    __syncthreads();
    for (int i = tid; i < m; i += BT) {
        int2 e = E[i];
        int pos = atomicAdd(&cntL[mapPrev[e.y]], 1);
        csrPrev[pos] = mapNew[e.x];
    }
    __syncthreads();
    for (int i = tid; i < bmw; i += BT) bmNew[i] = bmL[i];
    int L = lcnt;
    if (gzero) for (int i = tid; i < L; i += BT) gzero[i] = 0;
    if (tid == 0) { *cntNew = L; *mcntNext = 0; }
}

// ---- multi-block frontier discovery: E -> bm_out/Tnew/mapNew/soNew (+zero gcountNew slot) ----
__global__ __launch_bounds__(256) void discover_kernel(const int2* __restrict__ E,
                                                       const int* __restrict__ mcnt,
                                                       const float* __restrict__ invout,
                                                       unsigned* __restrict__ bm_out,
                                                       int* __restrict__ Tnew,
                                                       int* __restrict__ mapNew,
                                                       float* __restrict__ soNew,
                                                       int* __restrict__ cntNew,
                                                       int* __restrict__ gcountNew) {
    int m = *mcnt;
    int lane = threadIdx.x & 63;
    for (int i0 = blockIdx.x * 256; i0 < m; i0 += gridDim.x * 256) {
        int i = i0 + (int)threadIdx.x;
        int u = 0;
        bool flag = false;
        if (i < m) {
            u = E[i].x;
            unsigned old = atomicOr(&bm_out[u >> 5], 1u << (u & 31));
            flag = !((old >> (u & 31)) & 1);
        }
        unsigned long long mask = __ballot(flag);
        if (mask) {
            int leader = __ffsll((long long)mask) - 1;
            int b = 0;
            if (lane == leader) b = atomicAdd(cntNew, __popcll(mask));
            b = __shfl(b, leader);
            if (flag) {
                int sl = b + __popcll(mask & ((1ull << lane) - 1));
                Tnew[sl] = u;
                mapNew[u] = sl;
                soNew[sl] = invout[u];
                gcountNew[sl] = 0;
            }
        }
    }
}

// ---- per-level cursor scan (single block) + optional counter zero ----
__global__ __launch_bounds__(BT) void cursors_kernel(const int* __restrict__ gcount,
                                                     const int* __restrict__ cntL,
                                                     int* __restrict__ ends,
                                                     float* __restrict__ invin,
                                                     int* __restrict__ gcursor,
                                                     int* __restrict__ zeroA) {
    __shared__ int tmp[BT];
    int tid = threadIdx.x;
    int n1 = *cntL;
    if (tid == 0 && zeroA) *zeroA = 0;
    int carry = 0;
    for (int c0 = 0; c0 < n1; c0 += BT) {
        int v = (c0 + tid < n1) ? gcount[c0 + tid] : 0;
        __syncthreads();
        tmp[tid] = v;
        __syncthreads();
        for (int off = 1; off < BT; off <<= 1) {
            int t = (tid >= off) ? tmp[tid - off] : 0;
            __syncthreads();
            tmp[tid] += t;
            __syncthreads();
        }
        int incl = tmp[tid] + carry;
        int tot = tmp[BT - 1];
        if (c0 + tid < n1) {
            ends[c0 + tid] = incl;
            invin[c0 + tid] = rsqrtf(fmaxf((float)v, 1.0f));
            gcursor[c0 + tid] = incl - v;
        }
        carry += tot;
    }
}

// ---- multi-block CSR fill; mapNew==nullptr -> keep original src ids ----
__global__ __launch_bounds__(256) void fill_level(const int2* __restrict__ E,
                                                  const int* __restrict__ mcnt,
                                                  const int* __restrict__ mapPrev,
                                                  const int* __restrict__ mapNew,
                                                  int* __restrict__ gcursor,
                                                  int* __restrict__ csr) {
    int m = *mcnt;
    for (int i = blockIdx.x * 256 + threadIdx.x; i < m; i += gridDim.x * 256) {
        int2 e = E[i];
        int pos = atomicAdd(&gcursor[mapPrev[e.y]], 1);
        csr[pos] = mapNew ? mapNew[e.x] : e.x;
    }
}

// ---- fused layer: slot-dense CSR gather (LDS) + bf16 MFMA + invin/bias/LN/ReLU ----
template <int LAST, int FP32IN>
__global__ __launch_bounds__(256) void layer_fused(const void* __restrict__ FinV,
                                                   const float* __restrict__ edge_scale,
                                                   const int* __restrict__ ends,
                                                   const int* __restrict__ csr,
                                                   const short* __restrict__ Wt,
                                                   const float* __restrict__ invin_slot,
                                                   const float* __restrict__ so_slot,
                                                   const float* __restrict__ bias,
                                                   const float* __restrict__ gamma,
                                                   const float* __restrict__ beta,
                                                   const int* __restrict__ cnt,
                                                   unsigned short* __restrict__ Fout,
                                                   float* __restrict__ out) {
    const unsigned* Fb = (const unsigned*)FinV;
    const float4*  Ff = (const float4*)FinV;
    __shared__ short As[16][136];
    __shared__ float sstat[2][4][16];
    __shared__ float sinv[2][16];
    int tid = threadIdx.x;
    int w = tid >> 6, lane = tid & 63;
    int seg = lane >> 4, m = lane & 15;
    int n = *cnt;
    int tiles = (n + 15) >> 4;

    float bb[2], gg[2], pp[2];
#pragma unroll
    for (int j = 0; j < 2; j++) {
        int col = (w * 2 + j) * 16 + m;
        bb[j] = bias[col]; gg[j] = gamma[col]; pp[j] = beta[col];
    }

    for (int t = blockIdx.x; t < tiles; t += gridDim.x) {
        int base = t * 16;

        for (int q = 0; q < 4; q++) {
            int rr = w * 4 + q;
            int gr = base + rr;
            float ax[8];
#pragma unroll
            for (int k = 0; k < 8; k++) ax[k] = 0.f;
            if (gr < n) {
                int end = ends[gr];
                int e = (gr == 0) ? 0 : ends[gr - 1];
                while (e < end) {
                    int rem = end - e;
                    int myi = 0;
                    if (lane < rem) myi = csr[e + lane];
                    int nn = min(rem, 64);
                    int p = 0;
                    for (; p + 16 <= nn; p += 16) {
                        if (FP32IN) {
                            float4 fa[4], fb4[4]; float so[4];
#pragma unroll
                            for (int gi = 0; gi < 4; gi++) {
                                int idx = __shfl(myi, p + gi * 4 + seg);
                                so[gi] = edge_scale[idx];
                                const float4* qq = Ff + (size_t)idx * 32 + m * 2;
                                fa[gi] = qq[0]; fb4[gi] = qq[1];
                            }
#pragma unroll
                            for (int gi = 0; gi < 4; gi++) {
                                ax[0] += fa[gi].x * so[gi]; ax[1] += fa[gi].y * so[gi];
                                ax[2] += fa[gi].z * so[gi]; ax[3] += fa[gi].w * so[gi];
                                ax[4] += fb4[gi].x * so[gi]; ax[5] += fb4[gi].y * so[gi];
                                ax[6] += fb4[gi].z * so[gi]; ax[7] += fb4[gi].w * so[gi];
                            }
                        } else {
                            uint4 u[4];
#pragma unroll
                            for (int gi = 0; gi < 4; gi++) {
                                int idx = __shfl(myi, p + gi * 4 + seg);
                                u[gi] = *(const uint4*)(Fb + (size_t)idx * 64 + m * 4);
                            }
#pragma unroll
                            for (int gi = 0; gi < 4; gi++) {
                                ax[0] += __uint_as_float(u[gi].x << 16);
                                ax[1] += __uint_as_float(u[gi].x & 0xFFFF0000u);
                                ax[2] += __uint_as_float(u[gi].y << 16);
                                ax[3] += __uint_as_float(u[gi].y & 0xFFFF0000u);
                                ax[4] += __uint_as_float(u[gi].z << 16);
                                ax[5] += __uint_as_float(u[gi].z & 0xFFFF0000u);
                                ax[6] += __uint_as_float(u[gi].w << 16);
                                ax[7] += __uint_as_float(u[gi].w & 0xFFFF0000u);
                            }
                        }
                    }
                    for (; p < nn; p += 4) {
                        bool act = (p + seg) < nn;
                        int idx = __shfl(myi, (p + seg) & 63);
                        if (act) {
                            if (FP32IN) {
                                float so = edge_scale[idx];
                                const float4* qq = Ff + (size_t)idx * 32 + m * 2;
                                float4 fa = qq[0], fb4 = qq[1];
                                ax[0] += fa.x * so; ax[1] += fa.y * so;
                                ax[2] += fa.z * so; ax[3] += fa.w * so;
                                ax[4] += fb4.x * so; ax[5] += fb4.y * so;
                                ax[6] += fb4.z * so; ax[7] += fb4.w * so;
                            } else {
                                uint4 u = *(const uint4*)(Fb + (size_t)idx * 64 + m * 4);
                                ax[0] += __uint_as_float(u.x << 16);
                                ax[1] += __uint_as_float(u.x & 0xFFFF0000u);
                                ax[2] += __uint_as_float(u.y << 16);
                                ax[3] += __uint_as_float(u.y & 0xFFFF0000u);
                                ax[4] += __uint_as_float(u.z << 16);
                                ax[5] += __uint_as_float(u.z & 0xFFFF0000u);
                                ax[6] += __uint_as_float(u.w << 16);
                                ax[7] += __uint_as_float(u.w & 0xFFFF0000u);
                            }
                        }
                    }
                    e += nn;
                }
#pragma unroll
                for (int k = 0; k < 8; k++) {
                    ax[k] += __shfl_xor(ax[k], 16);
                    ax[k] += __shfl_xor(ax[k], 32);
                }
            }
            if (seg == 0) {
                uint4 o;
                o.x = (unsigned)f2bf(ax[0]) | ((unsigned)f2bf(ax[1]) << 16);
                o.y = (unsigned)f2bf(ax[2]) | ((unsigned)f2bf(ax[3]) << 16);
                o.z = (unsigned)f2bf(ax[4]) | ((unsigned)f2bf(ax[5]) << 16);
                o.w = (unsigned)f2bf(ax[6]) | ((unsigned)f2bf(ax[7]) << 16);
                *(uint4*)&As[rr][8 * m] = o;
            }
            if (lane == 0) {
                sinv[0][rr] = (gr < n) ? invin_slot[gr] : 1.f;
                sinv[1][rr] = (LAST || gr >= n) ? 1.f : so_slot[gr];
            }
        }
        __syncthreads();

        short8 a[4];
#pragma unroll
        for (int k0 = 0; k0 < 4; k0++)
            a[k0] = *(const short8*)&As[m][k0 * 32 + seg * 8];
        v4f acc[2];
        acc[0] = (v4f){0.f, 0.f, 0.f, 0.f};
        acc[1] = (v4f){0.f, 0.f, 0.f, 0.f};
#pragma unroll
        for (int k0 = 0; k0 < 4; k0++) {
#pragma unroll
            for (int j = 0; j < 2; j++) {
                int ct = w * 2 + j;
                short8 b = *(const short8*)(Wt + (size_t)((k0 * 8 + ct) * 64 + lane) * 8);
                acc[j] = __builtin_amdgcn_mfma_f32_16x16x32_bf16(a[k0], b, acc[j], 0, 0, 0);
            }
        }

        float x[4][2];
#pragma unroll
        for (int r = 0; r < 4; r++) {
            int row = seg * 4 + r;
            float iv = sinv[0][row];
            float s = 0.f, sq = 0.f;
#pragma unroll
            for (int j = 0; j < 2; j++) {
                float c = acc[j][r] * iv + bb[j];
                x[r][j] = c;
                s += c; sq += c * c;
            }
#pragma unroll
            for (int off = 1; off < 16; off <<= 1) {
                s  += __shfl_xor(s, off);
                sq += __shfl_xor(sq, off);
            }
            if (m == 0) { sstat[0][w][row] = s; sstat[1][w][row] = sq; }
        }
        __syncthreads();

#pragma unroll
        for (int r = 0; r < 4; r++) {
            int row = seg * 4 + r;
            int gr = base + row;
            if (gr >= n) continue;
            float s  = sstat[0][0][row] + sstat[0][1][row] + sstat[0][2][row] + sstat[0][3][row];
            float sq = sstat[1][0][row] + sstat[1][1][row] + sstat[1][2][row] + sstat[1][3][row];
            float mu = s * (1.0f / RANK);
            float var = sq * (1.0f / RANK) - mu * mu;
            float rs = rsqrtf(var + LN_EPS);
#pragma unroll
            for (int j = 0; j < 2; j++) {
                int col = (w * 2 + j) * 16 + m;
                float y = fmaxf((x[r][j] - mu) * rs * gg[j] + pp[j], 0.f);
                if (LAST) out[(size_t)gr * RANK + col] = y;
                else Fout[(size_t)gr * RANK + col] = f2bf(y * sinv[1][row]);
            }
        }
        __syncthreads();
    }
}

extern "C" void kernel_launch(void* const* d_in, const int* in_sizes, int n_in,
                              void* d_out, int out_size, void* d_ws, size_t ws_size,
                              hipStream_t stream) {
    const float* features = (const float*)d_in[0];
    const int* src = (const int*)d_in[1];
    const int* dst = (const int*)d_in[2];
    const int* bnn = (const int*)d_in[3];
    const float* Ws = (const float*)d_in[4];
    const float* bs = (const float*)d_in[5];
    const float* gammas = (const float*)d_in[6];
    const float* betas = (const float*)d_in[7];
    float* out = (float*)d_out;

    int M  = in_sizes[0] / RANK;   // 50000
    int nE = in_sizes[1];          // 640000
    int nG = in_sizes[3];          // 50

    char* ws = (char*)d_ws;
    size_t off = 0;
    auto alloc = [&](size_t bytes) {
        void* p = ws + off;
        off += (bytes + 255) & ~(size_t)255;
        return p;
    };
    unsigned short* psrc = (unsigned short*)alloc((size_t)ECH * BINS * 2);
    short* Wt      = (short*)alloc((size_t)3 * 16384 * 2);
    float* invout  = (float*)alloc((size_t)M * 4);
    int*   map3    = (int*)alloc((size_t)M * 4);
    int*   map2    = (int*)alloc((size_t)M * 4);
    int*   map1    = (int*)alloc((size_t)M * 4);
    int*   T3      = (int*)alloc((size_t)((nG + 63) & ~63) * 4);
    int*   T2      = (int*)alloc((size_t)M * 4);
    int*   T1      = (int*)alloc((size_t)M * 4);
    float* so2     = (float*)alloc((size_t)M * 4);
    float* so1     = (float*)alloc((size_t)M * 4);
    float* invin3  = (float*)alloc((size_t)((nG + 63) & ~63) * 4);
    float* invin2  = (float*)alloc((size_t)M * 4);
    float* invin1  = (float*)alloc((size_t)M * 4);
    int*   ends3   = (int*)alloc((size_t)((nG + 63) & ~63) * 4);
    int*   ends2   = (int*)alloc((size_t)M * 4);
    int*   ends1   = (int*)alloc((size_t)M * 4);
    int*   csr3    = (int*)alloc((size_t)nE * 4);
    int*   csr2    = (int*)alloc((size_t)nE * 4);
    int*   csr1    = (int*)alloc((size_t)nE * 4);
    int2*  E3      = (int2*)alloc((size_t)nE * 8);
    int2*  E2      = (int2*)alloc((size_t)nE * 8);
    int2*  E1      = (int2*)alloc((size_t)nE * 8);
    unsigned* bm3  = (unsigned*)alloc(BMWMAX * 4);
    unsigned* bm2  = (unsigned*)alloc(BMWMAX * 4);
    unsigned* bm1  = (unsigned*)alloc(BMWMAX * 4);
    int*   mcnt3   = (int*)alloc(256);
    int*   mcnt2   = (int*)alloc(256);
    int*   mcnt1   = (int*)alloc(256);
    int*   cnt3    = (int*)alloc(256);
    int*   cnt2    = (int*)alloc(256);
    int*   cnt1    = (int*)alloc(256);
    int*   gcount2 = (int*)alloc((size_t)M * 4);
    int*   gcursor2= (int*)alloc((size_t)M * 4);
    int*   gcount1 = (int*)alloc((size_t)M * 4);
    int*   gcursor1= (int*)alloc((size_t)M * 4);
    short* F1      = (short*)alloc((size_t)M * RANK * 2);
    short* F2      = (short*)alloc((size_t)M * RANK * 2);

    int nbR = (M + BT - 1) / BT;

    // K1: src histogram + W repack + T3 mark
    hist_mark<<<dim3(ECH + 2, NCH), BT, 0, stream>>>(src, Ws, Wt, bnn, nG, psrc,
                                                     T3, map3, bm3, mcnt3, cnt3, nE, M);
    // K2: invout reduce + T3 edge scan -> E3
    reduce_scan3<<<nbR + NSB, BT, 0, stream>>>(psrc, invout, M, nbR, src, dst, bm3, E3, mcnt3, nE);
    // K3: E3 -> T2/map2/so2/bm2 + CSR3; zero gcount2 slots, mcnt2, bm1, cnt1
    build_level<<<1, BT, 0, stream>>>(E3, mcnt3, map3, cnt3, invout, T2, map2, cnt2, so2,
                                      csr3, ends3, invin3, bm2, mcnt2, gcount2, bm1, cnt1, M);
    // K4: T2 edge scan -> E2 + per-T2-slot counts
    scan_match<1><<<NSB, BT, 0, stream>>>(src, dst, bm2, E2, mcnt2, gcount2, map2, nE, M);
    // K5: multi-block discover: E2 -> T1/map1/so1/bm1; zero gcount1 slots
    discover_kernel<<<64, 256, 0, stream>>>(E2, mcnt2, invout, bm1, T1, map1, so1, cnt1, gcount1);
    // K6: scan gcount2 -> ends2/invin2/gcursor2; zero mcnt1
    cursors_kernel<<<1, BT, 0, stream>>>(gcount2, cnt2, ends2, invin2, gcursor2, mcnt1);
    // K7: fill CSR2 (entries = T1 slots)
    fill_level<<<64, 256, 0, stream>>>(E2, mcnt2, map2, map1, gcursor2, csr2);
    // K8: T1 edge scan -> E1 + per-T1-slot counts
    scan_match<1><<<NSB, BT, 0, stream>>>(src, dst, bm1, E1, mcnt1, gcount1, map1, nE, M);
    // K9: scan gcount1 -> ends1/invin1/gcursor1
    cursors_kernel<<<1, BT, 0, stream>>>(gcount1, cnt1, ends1, invin1, gcursor1, nullptr);
    // K10: fill CSR1 (entries = original node ids)
    fill_level<<<64, 256, 0, stream>>>(E1, mcnt1, map1, nullptr, gcursor1, csr1);

    // K11-13: fused layers
    layer_fused<0, 1><<<512, 256, 0, stream>>>(features, invout, ends1, csr1, Wt,
                                               invin1, so1, bs, gammas, betas, cnt1,
                                               (unsigned short*)F1, nullptr);
    layer_fused<0, 0><<<64, 256, 0, stream>>>(F1, nullptr, ends2, csr2, Wt + 16384,
                                              invin2, so2, bs + RANK, gammas + RANK, betas + RANK,
                                              cnt2, (unsigned short*)F2, nullptr);
    layer_fused<1, 0><<<(nG + 15) / 16, 256, 0, stream>>>(F2, nullptr, ends3, csr3, Wt + 32768,
                                                          invin3, nullptr, bs + 2 * RANK,
                                                          gammas + 2 * RANK, betas + 2 * RANK,
                                                          cnt3, nullptr, out);
}

// Round 15
// 178.782 us; speedup vs baseline: 1.2918x; 1.1150x over previous
//
#include <hip/hip_runtime.h>

#define RANK 128
#define LN_EPS 1e-5f

// CSR-build geometry (M=50000, nE=640000)
#define NCH 2
#define CHUNK 25600            // NCH*CHUNK = 51200 >= M ; LDS = 100 KB
#define BINS (NCH * CHUNK)
#define ECH 64                 // edge chunks
#define BT 1024                // threads per CSR-build block
#define BMWL ((BINS + 31) / 32) // LDS bitmap words (6.4 KB)

using short8 = __attribute__((ext_vector_type(8))) short;
using v4f    = __attribute__((ext_vector_type(4))) float;

__device__ inline unsigned short f2bf(float f) {
    unsigned u = __float_as_uint(f);
    unsigned r = (u + 0x7FFF + ((u >> 16) & 1)) >> 16;   // RNE
    return (unsigned short)r;
}

// ---- partial histograms (u16, no global atomics) + W repack on spare blocks ----
__global__ __launch_bounds__(BT) void hist_part(const int* __restrict__ src,
                                                const int* __restrict__ dst,
                                                unsigned short* __restrict__ pdst,
                                                unsigned short* __restrict__ psrc,
                                                const float* __restrict__ Ws,
                                                short* __restrict__ Wt, int nE) {
    int c = blockIdx.x, n = blockIdx.y, z = blockIdx.z;
    if (c == ECH) {   // repack blocks: 4 blocks x 1024 threads, strided over 6144 sids
        int lin = n + NCH * z;
        for (int sid = lin * BT + (int)threadIdx.x; sid < 3 * 2048; sid += NCH * 2 * BT) {
            int l = sid >> 11;
            int s = sid & 2047;
            int lane = s & 63, ct = (s >> 6) & 7, k0 = s >> 9;
            int m = lane & 15, quad = lane >> 4;
            const float* W = Ws + (size_t)l * RANK * RANK;
            short* o = Wt + (size_t)l * 16384 + (size_t)s * 8;
#pragma unroll
            for (int j = 0; j < 8; j++)
                o[j] = (short)f2bf(W[(k0 * 32 + quad * 8 + j) * RANK + ct * 16 + m]);
        }
        return;
    }
    __shared__ int h[CHUNK];
    const int* arr = z ? src : dst;
    unsigned short* pout = z ? psrc : pdst;
    int base = n * CHUNK;
    for (int i = threadIdx.x; i < CHUNK; i += BT) h[i] = 0;
    __syncthreads();
    int epc = (nE + ECH - 1) / ECH;
    int e0 = c * epc, e1 = min(e0 + epc, nE);
    int tid = threadIdx.x;
    int a0 = min((e0 + 3) & ~3, e1);
    if (tid < a0 - e0) {
        int v = arr[e0 + tid] - base;
        if ((unsigned)v < (unsigned)CHUNK) atomicAdd(&h[v], 1);
    }
    int rem = e1 - a0;
    int nv = (rem > 0) ? (rem & ~3) : 0;
    for (int e = a0 + tid * 4; e < a0 + nv; e += BT * 4) {
        int4 v4 = *(const int4*)(arr + e);
        int v;
        v = v4.x - base; if ((unsigned)v < (unsigned)CHUNK) atomicAdd(&h[v], 1);
        v = v4.y - base; if ((unsigned)v < (unsigned)CHUNK) atomicAdd(&h[v], 1);
        v = v4.z - base; if ((unsigned)v < (unsigned)CHUNK) atomicAdd(&h[v], 1);
        v = v4.w - base; if ((unsigned)v < (unsigned)CHUNK) atomicAdd(&h[v], 1);
    }
    int t0 = a0 + nv;
    if (tid < e1 - t0) {
        int v = arr[t0 + tid] - base;
        if ((unsigned)v < (unsigned)CHUNK) atomicAdd(&h[v], 1);
    }
    __syncthreads();
    unsigned short* o = pout + (size_t)c * BINS + base;
    for (int i = threadIdx.x; i < CHUNK; i += BT) o[i] = (unsigned short)h[i];
}

// ------- reduce u16 partials -> counts/invin/invout + in-block inclusive scan -------
__global__ __launch_bounds__(256) void reduce_scan1(const unsigned short* __restrict__ pdst,
                                                    const unsigned short* __restrict__ psrc,
                                                    int* __restrict__ counts,
                                                    float* __restrict__ invin,
                                                    float* __restrict__ invout,
                                                    int* __restrict__ ends,
                                                    int* __restrict__ bsums, int M) {
    __shared__ int tmp[256];
    int tid = threadIdx.x;
    int gid = blockIdx.x * 256 + tid;
    int cd = 0, cs = 0;
    if (gid < M) {
#pragma unroll 8
        for (int c = 0; c < ECH; c++) {
            cd += pdst[(size_t)c * BINS + gid];
            cs += psrc[(size_t)c * BINS + gid];
        }
        counts[gid] = cd;
        invin[gid]  = rsqrtf(fmaxf((float)cd, 1.0f));
        invout[gid] = rsqrtf(fmaxf((float)cs, 1.0f));
    }
    tmp[tid] = cd;
    __syncthreads();
    for (int off = 1; off < 256; off <<= 1) {
        int t = (tid >= off) ? tmp[tid - off] : 0;
        __syncthreads();
        tmp[tid] += t;
        __syncthreads();
    }
    if (gid < M) ends[gid] = tmp[tid];
    if (tid == 255) bsums[blockIdx.x] = tmp[255];
}

// ------- global scan finish + per-(chunk,bin) int cursors -> pcur -------
__global__ __launch_bounds__(256) void scan23_offs(int* __restrict__ ends,
                                                   const int* __restrict__ counts,
                                                   const int* __restrict__ bsums,
                                                   const unsigned short* __restrict__ pdst,
                                                   int* __restrict__ pcur, int nb, int M) {
    __shared__ int red[256];
    int tid = threadIdx.x;
    int b = blockIdx.x;
    red[tid] = (tid < b && tid < nb) ? bsums[tid] : 0;   // nb <= 256
    __syncthreads();
    for (int off = 128; off > 0; off >>= 1) {
        if (tid < off) red[tid] += red[tid + off];
        __syncthreads();
    }
    int prefix = red[0];
    int gid = b * 256 + tid;
    if (gid < M) {
        int e = ends[gid] + prefix;   // inclusive global end
        ends[gid] = e;
        int run = e - counts[gid];    // exclusive start
#pragma unroll 8
        for (int c = 0; c < ECH; c++) {
            size_t idx = (size_t)c * BINS + gid;
            int t = pdst[idx];
            pcur[idx] = run;
            run += t;
        }
    }
}

// ---------------- CSR fill via LDS cursors (int4 edge loads) ----------------
__global__ __launch_bounds__(BT) void fill_sorted(const int* __restrict__ src,
                                                  const int* __restrict__ dst,
                                                  const int* __restrict__ pcur,
                                                  int* __restrict__ csr_src, int nE) {
    __shared__ int cur[CHUNK];
    int c = blockIdx.x, n = blockIdx.y;
    int base = n * CHUNK;
    const int* o = pcur + (size_t)c * BINS + base;
    for (int i = threadIdx.x; i < CHUNK; i += BT) cur[i] = o[i];
    __syncthreads();
    int epc = (nE + ECH - 1) / ECH;
    int e0 = c * epc, e1 = min(e0 + epc, nE);
    int tid = threadIdx.x;
    int a0 = min((e0 + 3) & ~3, e1);
    if (tid < a0 - e0) {
        int e = e0 + tid;
        int d = dst[e] - base;
        if ((unsigned)d < (unsigned)CHUNK) csr_src[atomicAdd(&cur[d], 1)] = src[e];
    }
    int rem = e1 - a0;
    int nv = (rem > 0) ? (rem & ~3) : 0;
    for (int e = a0 + tid * 4; e < a0 + nv; e += BT * 4) {
        int4 d4 = *(const int4*)(dst + e);
        int4 s4 = *(const int4*)(src + e);
        int d;
        d = d4.x - base; if ((unsigned)d < (unsigned)CHUNK) csr_src[atomicAdd(&cur[d], 1)] = s4.x;
        d = d4.y - base; if ((unsigned)d < (unsigned)CHUNK) csr_src[atomicAdd(&cur[d], 1)] = s4.y;
        d = d4.z - base; if ((unsigned)d < (unsigned)CHUNK) csr_src[atomicAdd(&cur[d], 1)] = s4.z;
        d = d4.w - base; if ((unsigned)d < (unsigned)CHUNK) csr_src[atomicAdd(&cur[d], 1)] = s4.w;
    }
    int t0 = a0 + nv;
    if (tid < e1 - t0) {
        int e = t0 + tid;
        int d = dst[e] - base;
        if ((unsigned)d < (unsigned)CHUNK) csr_src[atomicAdd(&cur[d], 1)] = src[e];
    }
}

// ------- T3 build + T3->T2 frontier in one single-block kernel (LDS bitmap) -------
// also zeroes bm1 (global) + cnt1 for the downstream frontier_csr
__global__ __launch_bounds__(256) void mark_expand3(const int* __restrict__ bnn, int nG,
                                                    const int* __restrict__ ends,
                                                    const int* __restrict__ csr_src,
                                                    int* __restrict__ T3, int* __restrict__ cnt3,
                                                    int* __restrict__ T2, int* __restrict__ cnt2,
                                                    unsigned* __restrict__ bm1,
                                                    int* __restrict__ cnt1, int M) {
    __shared__ unsigned bm[BMWL];
    __shared__ int lcnt;
    int tid = threadIdx.x;
    int bmw = (M + 31) / 32;
    for (int i = tid; i < BMWL; i += 256) bm[i] = 0;
    for (int i = tid; i < bmw; i += 256) bm1[i] = 0;
    if (tid == 0) { lcnt = 0; *cnt1 = 0; }
    __syncthreads();
    if (tid < 64) {
        int lane = tid;
        if (nG <= 64) {
            int v = (lane < nG) ? bnn[lane] : 0;
            int orig = v;
#pragma unroll
            for (int off = 1; off < 64; off <<= 1) {
                int t = __shfl_up(v, off);
                if (lane >= off) v += t;
            }
            int excl = v - orig;
            if (lane < nG) T3[lane] = excl;
            if (lane == 0) *cnt3 = nG;
        } else if (lane == 0) {
            int idx = 0;
            for (int g = 0; g < nG; g++) { T3[g] = idx; idx += bnn[g]; }
            *cnt3 = nG;
        }
    }
    __syncthreads();
    int lane = tid & 63, w = tid >> 6;
    for (int i = w; i < nG; i += 4) {
        int node = T3[i];
        int end = ends[node];
        int beg = (node == 0) ? 0 : ends[node - 1];
        for (int e0 = beg; e0 < end; e0 += 64) {
            if (e0 + lane < end) {
                int u = csr_src[e0 + lane];
                unsigned old = atomicOr(&bm[u >> 5], 1u << (u & 31));   // LDS
                if (!((old >> (u & 31)) & 1)) {
                    int pos = atomicAdd(&lcnt, 1);                      // LDS
                    T2[pos] = u;
                }
            }
        }
    }
    __syncthreads();
    if (tid == 0) *cnt2 = lcnt;
}

// ------- T2->T1 frontier via CSR ranges (global bitmap dedupe) -------
__global__ __launch_bounds__(256) void frontier_csr(const int* __restrict__ list,
                                                    const int* __restrict__ cnt,
                                                    const int* __restrict__ ends,
                                                    const int* __restrict__ csr_src,
                                                    unsigned* __restrict__ bm_out,
                                                    int* __restrict__ out_list,
                                                    int* __restrict__ out_cnt) {
    int lane = threadIdx.x & 63;
    int wg = blockIdx.x * 4 + (threadIdx.x >> 6);
    int nW = gridDim.x * 4;
    int n = *cnt;
    for (int i = wg; i < n; i += nW) {
        int node = list[i];
        int end = ends[node];
        int beg = (node == 0) ? 0 : ends[node - 1];
        for (int e0 = beg; e0 < end; e0 += 64) {
            int u = 0;
            bool flag = false;
            if (e0 + lane < end) {
                u = csr_src[e0 + lane];
                unsigned old = atomicOr(&bm_out[u >> 5], 1u << (u & 31));
                flag = !((old >> (u & 31)) & 1);
            }
            unsigned long long mask = __ballot(flag);
            if (mask) {
                int leader = __ffsll((long long)mask) - 1;
                int base = 0;
                if (lane == leader) base = atomicAdd(out_cnt, __popcll(mask));
                base = __shfl(base, leader);
                if (flag) out_list[base + __popcll(mask & ((1ull << lane) - 1))] = u;
            }
        }
    }
}

// ---- fused layer: CSR gather (LDS) + bf16 MFMA GEMM + invin/bias/LN/ReLU ----
// FP32IN: input rows are fp32 (features) scaled per-edge by edge_scale (invout)
template <int LAST, int FP32IN>
__global__ __launch_bounds__(256) void layer_fused(const void* __restrict__ FinV,
                                                   const float* __restrict__ edge_scale,
                                                   const int* __restrict__ ends,
                                                   const int* __restrict__ csr,
                                                   const short* __restrict__ Wt,
                                                   const float* __restrict__ invin,
                                                   const float* __restrict__ invout,
                                                   const float* __restrict__ bias,
                                                   const float* __restrict__ gamma,
                                                   const float* __restrict__ beta,
                                                   const int* __restrict__ list,
                                                   const int* __restrict__ cnt,
                                                   unsigned short* __restrict__ Fout,
                                                   float* __restrict__ out) {
    const unsigned* Fb = (const unsigned*)FinV;
    const float4*  Ff = (const float4*)FinV;
    __shared__ short As[16][136];
    __shared__ float sstat[2][4][16];
    __shared__ float sinv[2][16];
    __shared__ int snode[16];
    int tid = threadIdx.x;
    int w = tid >> 6, lane = tid & 63;
    int seg = lane >> 4, m = lane & 15;
    int n = *cnt;
    int tiles = (n + 15) >> 4;

    float bb[2], gg[2], pp[2];
#pragma unroll
    for (int j = 0; j < 2; j++) {
        int col = (w * 2 + j) * 16 + m;
        bb[j] = bias[col]; gg[j] = gamma[col]; pp[j] = beta[col];
    }

    for (int t = blockIdx.x; t < tiles; t += gridDim.x) {
        int base = t * 16;

        // ---- phase 1: gather 16 rows into LDS ----
        for (int q = 0; q < 4; q++) {
            int rr = w * 4 + q;
            int gr = base + rr;
            float ax[8];
#pragma unroll
            for (int k = 0; k < 8; k++) ax[k] = 0.f;
            int node = -1;
            if (gr < n) {
                node = list[gr];
                int end = ends[node];
                int e = (node == 0) ? 0 : ends[node - 1];
                while (e < end) {
                    int rem = end - e;
                    int myi = 0;
                    if (lane < rem) myi = csr[e + lane];
                    int nn = min(rem, 64);
                    int p = 0;
                    for (; p + 16 <= nn; p += 16) {
                        if (FP32IN) {
                            float4 fa[4], fb4[4]; float so[4];
#pragma unroll
                            for (int gi = 0; gi < 4; gi++) {
                                int idx = __shfl(myi, p + gi * 4 + seg);
                                so[gi] = edge_scale[idx];
                                const float4* qq = Ff + (size_t)idx * 32 + m * 2;
                                fa[gi] = qq[0]; fb4[gi] = qq[1];
                            }
#pragma unroll
                            for (int gi = 0; gi < 4; gi++) {
                                ax[0] += fa[gi].x * so[gi]; ax[1] += fa[gi].y * so[gi];
                                ax[2] += fa[gi].z * so[gi]; ax[3] += fa[gi].w * so[gi];
                                ax[4] += fb4[gi].x * so[gi]; ax[5] += fb4[gi].y * so[gi];
                                ax[6] += fb4[gi].z * so[gi]; ax[7] += fb4[gi].w * so[gi];
                            }
                        } else {
                            uint4 u[4];
#pragma unroll
                            for (int gi = 0; gi < 4; gi++) {
                                int idx = __shfl(myi, p + gi * 4 + seg);
                                u[gi] = *(const uint4*)(Fb + (size_t)idx * 64 + m * 4);
                            }
#pragma unroll
                            for (int gi = 0; gi < 4; gi++) {
                                ax[0] += __uint_as_float(u[gi].x << 16);
                                ax[1] += __uint_as_float(u[gi].x & 0xFFFF0000u);
                                ax[2] += __uint_as_float(u[gi].y << 16);
                                ax[3] += __uint_as_float(u[gi].y & 0xFFFF0000u);
                                ax[4] += __uint_as_float(u[gi].z << 16);
                                ax[5] += __uint_as_float(u[gi].z & 0xFFFF0000u);
                                ax[6] += __uint_as_float(u[gi].w << 16);
                                ax[7] += __uint_as_float(u[gi].w & 0xFFFF0000u);
                            }
                        }
                    }
                    for (; p < nn; p += 4) {
                        bool act = (p + seg) < nn;
                        int idx = __shfl(myi, (p + seg) & 63);
                        if (act) {
                            if (FP32IN) {
                                float so = edge_scale[idx];
                                const float4* qq = Ff + (size_t)idx * 32 + m * 2;
                                float4 fa = qq[0], fb4 = qq[1];
                                ax[0] += fa.x * so; ax[1] += fa.y * so;
                                ax[2] += fa.z * so; ax[3] += fa.w * so;
                                ax[4] += fb4.x * so; ax[5] += fb4.y * so;
                                ax[6] += fb4.z * so; ax[7] += fb4.w * so;
                            } else {
                                uint4 u = *(const uint4*)(Fb + (size_t)idx * 64 + m * 4);
                                ax[0] += __uint_as_float(u.x << 16);
                                ax[1] += __uint_as_float(u.x & 0xFFFF0000u);
                                ax[2] += __uint_as_float(u.y << 16);
                                ax[3] += __uint_as_float(u.y & 0xFFFF0000u);
                                ax[4] += __uint_as_float(u.z << 16);
                                ax[5] += __uint_as_float(u.z & 0xFFFF0000u);
                                ax[6] += __uint_as_float(u.w << 16);
                                ax[7] += __uint_as_float(u.w & 0xFFFF0000u);
                            }
                        }
                    }
                    e += nn;
                }
#pragma unroll
                for (int k = 0; k < 8; k++) {
                    ax[k] += __shfl_xor(ax[k], 16);
                    ax[k] += __shfl_xor(ax[k], 32);
                }
            }
            if (seg == 0) {   // lane m holds cols 8m..8m+7 of row rr
                uint4 o;
                o.x = (unsigned)f2bf(ax[0]) | ((unsigned)f2bf(ax[1]) << 16);
                o.y = (unsigned)f2bf(ax[2]) | ((unsigned)f2bf(ax[3]) << 16);
                o.z = (unsigned)f2bf(ax[4]) | ((unsigned)f2bf(ax[5]) << 16);
                o.w = (unsigned)f2bf(ax[6]) | ((unsigned)f2bf(ax[7]) << 16);
                *(uint4*)&As[rr][8 * m] = o;
            }
            if (lane == 0) {
                snode[rr] = node;
                sinv[0][rr] = (node >= 0) ? invin[node] : 1.f;
                sinv[1][rr] = (node >= 0) ? invout[node] : 1.f;
            }
        }
        __syncthreads();

        // ---- phase 2: MFMA (wave w covers cols w*32..w*32+31) ----
        short8 a[4];
#pragma unroll
        for (int k0 = 0; k0 < 4; k0++)
            a[k0] = *(const short8*)&As[m][k0 * 32 + seg * 8];
        v4f acc[2];
        acc[0] = (v4f){0.f, 0.f, 0.f, 0.f};
        acc[1] = (v4f){0.f, 0.f, 0.f, 0.f};
#pragma unroll
        for (int k0 = 0; k0 < 4; k0++) {
#pragma unroll
            for (int j = 0; j < 2; j++) {
                int ct = w * 2 + j;
                short8 b = *(const short8*)(Wt + (size_t)((k0 * 8 + ct) * 64 + lane) * 8);
                acc[j] = __builtin_amdgcn_mfma_f32_16x16x32_bf16(a[k0], b, acc[j], 0, 0, 0);
            }
        }

        float x[4][2];
#pragma unroll
        for (int r = 0; r < 4; r++) {
            int row = seg * 4 + r;
            float iv = sinv[0][row];
            float s = 0.f, sq = 0.f;
#pragma unroll
            for (int j = 0; j < 2; j++) {
                float c = acc[j][r] * iv + bb[j];
                x[r][j] = c;
                s += c; sq += c * c;
            }
#pragma unroll
            for (int off = 1; off < 16; off <<= 1) {
                s  += __shfl_xor(s, off);
                sq += __shfl_xor(sq, off);
            }
            if (m == 0) { sstat[0][w][row] = s; sstat[1][w][row] = sq; }
        }
        __syncthreads();

#pragma unroll
        for (int r = 0; r < 4; r++) {
            int row = seg * 4 + r;
            int gr = base + row;
            if (gr >= n) continue;
            float s  = sstat[0][0][row] + sstat[0][1][row] + sstat[0][2][row] + sstat[0][3][row];
            float sq = sstat[1][0][row] + sstat[1][1][row] + sstat[1][2][row] + sstat[1][3][row];
            float mu = s * (1.0f / RANK);
            float var = sq * (1.0f / RANK) - mu * mu;
            float rs = rsqrtf(var + LN_EPS);
#pragma unroll
            for (int j = 0; j < 2; j++) {
                int col = (w * 2 + j) * 16 + m;
                float y = fmaxf((x[r][j] - mu) * rs * gg[j] + pp[j], 0.f);
                if (LAST) {
                    out[(size_t)gr * RANK + col] = y;
                } else {
                    Fout[(size_t)snode[row] * RANK + col] = f2bf(y * sinv[1][row]);
                }
            }
        }
        __syncthreads();
    }
}

extern "C" void kernel_launch(void* const* d_in, const int* in_sizes, int n_in,
                              void* d_out, int out_size, void* d_ws, size_t ws_size,
                              hipStream_t stream) {
    const float* features = (const float*)d_in[0];
    const int* src = (const int*)d_in[1];
    const int* dst = (const int*)d_in[2];
    const int* bnn = (const int*)d_in[3];
    const float* Ws = (const float*)d_in[4];
    const float* bs = (const float*)d_in[5];
    const float* gammas = (const float*)d_in[6];
    const float* betas = (const float*)d_in[7];
    float* out = (float*)d_out;

    int M  = in_sizes[0] / RANK;   // 50000
    int nE = in_sizes[1];          // 640000
    int nG = in_sizes[3];          // 50
    int bmw = (M + 31) / 32;

    char* ws = (char*)d_ws;
    size_t off = 0;
    auto alloc = [&](size_t bytes) {
        void* p = ws + off;
        off += (bytes + 255) & ~(size_t)255;
        return p;
    };
    int*   counts  = (int*)alloc((size_t)M * 4);
    int*   ends    = (int*)alloc((size_t)M * 4);
    int*   bsums   = (int*)alloc(256 * 4);
    float* invout  = (float*)alloc((size_t)M * 4);
    float* invin   = (float*)alloc((size_t)M * 4);
    int*   csr_src = (int*)alloc((size_t)nE * 4);
    short* Wt      = (short*)alloc((size_t)3 * 16384 * 2);
    short* F1      = (short*)alloc((size_t)M * RANK * 2);
    short* F2      = (short*)alloc((size_t)M * RANK * 2);
    unsigned short* pdst = (unsigned short*)alloc((size_t)ECH * BINS * 2);  // 6.55 MB
    unsigned short* psrc = (unsigned short*)alloc((size_t)ECH * BINS * 2);  // 6.55 MB
    int*   pcur    = (int*)alloc((size_t)ECH * BINS * 4);                    // 13.1 MB
    unsigned* bm1  = (unsigned*)alloc((size_t)bmw * 4);
    int*   cnt1    = (int*)alloc(256);
    int*   cnt2    = (int*)alloc(256);
    int*   cnt3    = (int*)alloc(256);
    int*   T3      = (int*)alloc((size_t)((nG + 63) & ~63) * 4);
    int*   T2      = (int*)alloc((size_t)M * 4);
    int*   T1      = (int*)alloc((size_t)M * 4);

    int nb = (M + 255) / 256;   // 196 <= 256 (required by scan23_offs)

    // ---- CSR build (4 kernels; hist also repacks W on spare blocks) ----
    hist_part<<<dim3(ECH + 1, NCH, 2), BT, 0, stream>>>(src, dst, pdst, psrc, Ws, Wt, nE);
    reduce_scan1<<<nb, 256, 0, stream>>>(pdst, psrc, counts, invin, invout, ends, bsums, M);
    scan23_offs<<<nb, 256, 0, stream>>>(ends, counts, bsums, pdst, pcur, nb, M);
    fill_sorted<<<dim3(ECH, NCH), BT, 0, stream>>>(src, dst, pcur, csr_src, nE);

    // ---- frontiers (2 kernels; mark_expand3 zeroes bm1/cnt1) ----
    mark_expand3<<<1, 256, 0, stream>>>(bnn, nG, ends, csr_src, T3, cnt3, T2, cnt2, bm1, cnt1, M);
    frontier_csr<<<64, 256, 0, stream>>>(T2, cnt2, ends, csr_src, bm1, T1, cnt1);

    // ---- fused layers (3 kernels); L1 reads fp32 features w/ per-edge invout ----
    layer_fused<0, 1><<<512, 256, 0, stream>>>(features, invout, ends, csr_src, Wt,
                                               invin, invout, bs, gammas, betas,
                                               T1, cnt1, (unsigned short*)F1, nullptr);
    layer_fused<0, 0><<<64, 256, 0, stream>>>(F1, nullptr, ends, csr_src, Wt + 16384,
                                              invin, invout, bs + RANK, gammas + RANK, betas + RANK,
                                              T2, cnt2, (unsigned short*)F2, nullptr);
    layer_fused<1, 0><<<(nG + 15) / 16, 256, 0, stream>>>(F2, nullptr, ends, csr_src, Wt + 32768,
                                                          invin, invout, bs + 2 * RANK,
                                                          gammas + 2 * RANK, betas + 2 * RANK,
                                                          T3, cnt3, nullptr, out);
}